// Round 3
// baseline (15574.846 us; speedup 1.0000x reference)
//
#include <hip/hip_runtime.h>
#include <hip/hip_bf16.h>

#define NIN 32
#define NHID 128
#define NOUT 16
#define NIN1 160   // NIN+NHID
#define SEQT 512
#define NBATCH 256

__device__ __forceinline__ float bf2f(__hip_bfloat16 v) { return __bfloat162float(v); }
__device__ __forceinline__ float us2f(unsigned short u) {
    return __uint_as_float(((unsigned int)u) << 16);
}

// Knots: t_m = -8.8 + 1.6*m, m = 0..11  (G=5, K=3, range [-4,4], h=1.6)
// 4 (boundary-truncated) nonzero cubic basis values; out4[r] is basis js+r, js in [0,4].
__device__ __forceinline__ void spline_feat(float c, float* out4, int* jst) {
    const float t0 = -8.8f, hh = 1.6f;
    int m0 = (int)floorf((c - t0) / hh);
    bool valid = (m0 >= 0) && (m0 <= 10);
    float v0 = 1.f, v1 = 0.f, v2 = 0.f, v3 = 0.f;
    #pragma unroll
    for (int d = 1; d <= 3; ++d) {
        float inv = 1.f / (d * hh);
        float nv[4];
        float pv[4] = {v0, v1, v2, v3};
        #pragma unroll
        for (int r = 3; r >= 0; --r) {
            if (r > d) { nv[r] = 0.f; continue; }
            int m = m0 - d + r;
            float tm = t0 + hh * (float)m;
            float left  = (r >= 1) ? pv[r-1] : 0.f;
            float right = (r <= d-1) ? pv[r] : 0.f;
            nv[r] = ((c - tm) * left + (tm + hh * (float)(d+1) - c) * right) * inv;
        }
        v0 = nv[0]; v1 = nv[1]; v2 = nv[2]; v3 = nv[3];
    }
    float v[4] = {v0, v1, v2, v3};
    int jb = m0 - 3;
    int js = jb < 0 ? 0 : (jb > 4 ? 4 : jb);
    int sh = js - jb;                 // stored[r] = v[r+sh]
    #pragma unroll
    for (int r = 0; r < 4; ++r) {
        int rs = r + sh;
        out4[r] = (valid && rs >= 0 && rs <= 3) ? v[rs] : 0.f;
    }
    *jst = js;
}

__device__ __forceinline__ float sel4(int d, float4 b) {
    return d == 0 ? b.x : (d == 1 ? b.y : (d == 2 ? b.z : b.w));
}

// Block-uniform dtype sniff: sample 256 EVEN ushort indices of x (always within the
// bf16-size bound count*2 bytes). bf16 data -> sane values; fp32 data -> even halves
// are mantissa bits -> ~92% insane. Deterministic, identical every call (graph-safe).
__device__ int detect_is_f32(const void* x, int tid, int* sh) {
    if (tid == 0) *sh = 0;
    __syncthreads();
    if (tid < 64) {
        const unsigned short* p = (const unsigned short*)x;
        int bad = 0;
        #pragma unroll
        for (int q = 0; q < 4; ++q) {
            int u = 2 * ((tid * 4 + q) * 8191);   // max 4,177,410 < 4,194,304
            float v = us2f(p[u]);
            float a = fabsf(v);
            bool sane = (v == 0.0f) || (a >= 1e-30f && a <= 1e3f);  // NaN/Inf -> insane
            bad += sane ? 0 : 1;
        }
        if (bad) atomicAdd(sh, bad);
    }
    __syncthreads();
    return (*sh > 64) ? 1 : 0;
}

template<bool F32>
__device__ __forceinline__ float ldw(const void* p, size_t i) {
    return F32 ? ((const float*)p)[i] : bf2f(((const __hip_bfloat16*)p)[i]);
}

template<bool F32>
__device__ __forceinline__ void ldrow8(const void* p, size_t row, float* cf) {
    if (F32) {
        const float4* cp = (const float4*)((const float*)p + row * 8);
        float4 a = cp[0], b = cp[1];
        cf[0]=a.x; cf[1]=a.y; cf[2]=a.z; cf[3]=a.w;
        cf[4]=b.x; cf[5]=b.y; cf[6]=b.z; cf[7]=b.w;
    } else {
        union { float4 f; __hip_bfloat16 h[8]; } u;
        u.f = *(const float4*)((const __hip_bfloat16*)p + row * 8);
        #pragma unroll
        for (int k = 0; k < 8; ++k) cf[k] = bf2f(u.h[k]);
    }
}

template<bool F32>
__device__ void kan_body(const void* __restrict__ x,
                         const void* __restrict__ coef1,
                         const void* __restrict__ sb1,
                         const void* __restrict__ sp1,
                         const void* __restrict__ coef2,
                         const void* __restrict__ sb2,
                         const void* __restrict__ sp2,
                         void* __restrict__ out,
                         float (&Fs)[2][NIN1][8], float (&red)[2][4][NHID],
                         int tid, int b0)
{
    const int o   = tid & 127;
    const int seg = tid >> 7;           // 0..3, inputs [seg*40, seg*40+40)

    for (int idx = tid; idx < 2 * 4 * NHID; idx += 512)
        ((float*)red)[idx] = 0.f;       // h0 = 0
    __syncthreads();

    for (int t = 0; t < SEQT; ++t) {
        // ---- phase 1: features (silu + sparse basis) for both batch rows ----
        if (tid < 2 * NIN1) {
            int be = (tid >= NIN1) ? 1 : 0;
            int i = tid - be * NIN1;
            float c;
            if (i < NIN) {
                size_t xi = ((size_t)(b0 + be) * SEQT + t) * NIN + i;
                c = ldw<F32>(x, xi);
            } else {
                int hi = i - NIN;
                c = red[be][0][hi] + red[be][1][hi] + red[be][2][hi] + red[be][3][hi];
            }
            float sil = c / (1.f + __expf(-c));
            float b4[4]; int js;
            spline_feat(c, b4, &js);
            float* F = &Fs[be][i][0];
            F[0] = b4[0]; F[1] = b4[1]; F[2] = b4[2]; F[3] = b4[3];
            F[4] = sil;   F[5] = (float)js;
        }
        __syncthreads();
        // ---- phase 2: matvec, weights shared across the two batch rows ----
        float acc0 = 0.f, acc1 = 0.f;
        const int ibase = seg * 40;
        for (int ii = 0; ii < 40; ++ii) {
            int i = ibase + ii;
            float4 ba  = *(const float4*)&Fs[0][i][0];
            float2 sj0 = *(const float2*)&Fs[0][i][4];
            float4 bb  = *(const float4*)&Fs[1][i][0];
            float2 sj1 = *(const float2*)&Fs[1][i][4];
            int j0 = (int)sj0.y; j0 = j0 < 0 ? 0 : (j0 > 4 ? 4 : j0);
            int j1 = (int)sj1.y; j1 = j1 < 0 ? 0 : (j1 > 4 ? 4 : j1);
            float w  = ldw<F32>(sb1, (size_t)i * NHID + o);
            float sp = ldw<F32>(sp1, (size_t)i * NHID + o);
            acc0 += sj0.x * w;
            acc1 += sj1.x * w;
            float cf[8];
            ldrow8<F32>(coef1, (size_t)i * NHID + o, cf);
            float s0 = 0.f, s1 = 0.f;
            #pragma unroll
            for (int k = 0; k < 8; ++k) {
                float t0v = (k >= j0 && k <= j0 + 3) ? sel4(k - j0, ba) : 0.f;
                float t1v = (k >= j1 && k <= j1 + 3) ? sel4(k - j1, bb) : 0.f;
                s0 += t0v * cf[k];
                s1 += t1v * cf[k];
            }
            acc0 += sp * s0;
            acc1 += sp * s1;
        }
        red[0][seg][o] = acc0;
        red[1][seg][o] = acc1;
        __syncthreads();
    }

    // ---- layer 2, final timestep only: h(=sum of red) -> out[b, 0..15] ----
    if (tid < 2 * NHID) {
        int be = tid >> 7, i = tid & 127;
        float c = red[be][0][i] + red[be][1][i] + red[be][2][i] + red[be][3][i];
        float sil = c / (1.f + __expf(-c));
        float b4[4]; int js;
        spline_feat(c, b4, &js);
        float* F = &Fs[be][i][0];
        F[0] = b4[0]; F[1] = b4[1]; F[2] = b4[2]; F[3] = b4[3];
        F[4] = sil;   F[5] = (float)js;
    }
    __syncthreads();
    if (tid < 2 * NOUT) {
        int be = tid >> 4, oo = tid & 15;
        float acc = 0.f;
        for (int i = 0; i < NHID; ++i) {
            float4 ba = *(const float4*)&Fs[be][i][0];
            float2 sj = *(const float2*)&Fs[be][i][4];
            int j = (int)sj.y; j = j < 0 ? 0 : (j > 4 ? 4 : j);
            float cf[8];
            ldrow8<F32>(coef2, (size_t)i * NOUT + oo, cf);
            float s = 0.f;
            #pragma unroll
            for (int k = 0; k < 8; ++k) {
                float tv = (k >= j && k <= j + 3) ? sel4(k - j, ba) : 0.f;
                s += tv * cf[k];
            }
            acc += sj.x * ldw<F32>(sb2, (size_t)i * NOUT + oo)
                 + ldw<F32>(sp2, (size_t)i * NOUT + oo) * s;
        }
        size_t oi = (size_t)(b0 + be) * NOUT + oo;
        if (F32) ((float*)out)[oi] = acc;
        else     ((__hip_bfloat16*)out)[oi] = __float2bfloat16(acc);
    }
}

__global__ __launch_bounds__(512, 1)
void kan_seq_kernel(const void* __restrict__ x,
                    const void* __restrict__ coef1,
                    const void* __restrict__ sb1,
                    const void* __restrict__ sp1,
                    const void* __restrict__ coef2,
                    const void* __restrict__ sb2,
                    const void* __restrict__ sp2,
                    void* __restrict__ out)
{
    __shared__ __align__(16) float Fs[2][NIN1][8];
    __shared__ __align__(16) float red[2][4][NHID];
    __shared__ int sh_flag;
    const int tid = threadIdx.x;
    const int b0 = blockIdx.x * 2;
    int isf32 = detect_is_f32(x, tid, &sh_flag);   // block-uniform
    if (isf32) kan_body<true >(x, coef1, sb1, sp1, coef2, sb2, sp2, out, Fs, red, tid, b0);
    else       kan_body<false>(x, coef1, sb1, sp1, coef2, sb2, sp2, out, Fs, red, tid, b0);
}

extern "C" void kernel_launch(void* const* d_in, const int* in_sizes, int n_in,
                              void* d_out, int out_size, void* d_ws, size_t ws_size,
                              hipStream_t stream) {
    kan_seq_kernel<<<NBATCH / 2, 512, 0, stream>>>(
        d_in[0], d_in[1], d_in[2], d_in[3], d_in[4], d_in[5], d_in[6], d_out);
}

// Round 4
// 1084.030 us; speedup vs baseline: 14.3675x; 14.3675x over previous
//
#include <hip/hip_runtime.h>
#include <hip/hip_bf16.h>

#define NIN 32
#define NHID 128
#define NOUT 16
#define NIN1 160   // NIN+NHID
#define SEQT 512
#define NB 256
#define SEGI 40    // i's per segment (4 segments x 128 o = 512 threads)

#if defined(__has_builtin)
#if __has_builtin(__builtin_amdgcn_fdot2_f32_bf16)
#define HAVE_DOT2BF 1
#endif
#endif
#ifndef HAVE_DOT2BF
#define HAVE_DOT2BF 0
#endif

// manual RNE f32->bf16 (inputs are finite/sane here)
__device__ __forceinline__ unsigned int f2bfbits(float f) {
    unsigned int u = __float_as_uint(f);
    return (u + 0x7fffu + ((u >> 16) & 1u)) >> 16;
}
__device__ __forceinline__ unsigned int packbf(float lo, float hi) {
    return f2bfbits(lo) | (f2bfbits(hi) << 16);
}

#if HAVE_DOT2BF
typedef __bf16 bf16x2 __attribute__((ext_vector_type(2)));
__device__ __forceinline__ float dot2w(unsigned int a, unsigned int b, float c) {
    return __builtin_amdgcn_fdot2_f32_bf16(__builtin_bit_cast(bf16x2, a),
                                           __builtin_bit_cast(bf16x2, b), c, false);
}
#else
__device__ __forceinline__ float dot2w(unsigned int a, unsigned int b, float c) {
    float alo = __uint_as_float(a << 16), ahi = __uint_as_float(a & 0xffff0000u);
    float blo = __uint_as_float(b << 16), bhi = __uint_as_float(b & 0xffff0000u);
    return __builtin_fmaf(ahi, bhi, __builtin_fmaf(alo, blo, c));
}
#endif

// Knots: t_m = -8.8 + 1.6*m (G=5, K=3, range [-4,4]); verified in round-3 PASS.
__device__ __forceinline__ void spline_feat(float c, float* out4, int* jst) {
    const float t0 = -8.8f, hh = 1.6f;
    int m0 = (int)floorf((c - t0) / hh);
    bool valid = (m0 >= 0) && (m0 <= 10);
    float v0 = 1.f, v1 = 0.f, v2 = 0.f, v3 = 0.f;
    #pragma unroll
    for (int d = 1; d <= 3; ++d) {
        float inv = 1.f / (d * hh);
        float nv[4];
        float pv[4] = {v0, v1, v2, v3};
        #pragma unroll
        for (int r = 3; r >= 0; --r) {
            if (r > d) { nv[r] = 0.f; continue; }
            int m = m0 - d + r;
            float tm = t0 + hh * (float)m;
            float left  = (r >= 1) ? pv[r-1] : 0.f;
            float right = (r <= d-1) ? pv[r] : 0.f;
            nv[r] = ((c - tm) * left + (tm + hh * (float)(d+1) - c) * right) * inv;
        }
        v0 = nv[0]; v1 = nv[1]; v2 = nv[2]; v3 = nv[3];
    }
    float v[4] = {v0, v1, v2, v3};
    int jb = m0 - 3;
    int js = jb < 0 ? 0 : (jb > 4 ? 4 : jb);
    int sh = js - jb;
    #pragma unroll
    for (int r = 0; r < 4; ++r) {
        int rs = r + sh;
        out4[r] = (valid && rs >= 0 && rs <= 3) ? v[rs] : 0.f;
    }
    *jst = js;
}

__global__ __launch_bounds__(512, 2)
void kan_seq(const float* __restrict__ x,
             const float* __restrict__ coef1,
             const float* __restrict__ sb1,
             const float* __restrict__ sp1,
             const float* __restrict__ coef2,
             const float* __restrict__ sb2,
             const float* __restrict__ sp2,
             float* __restrict__ out)
{
    __shared__ __align__(16) unsigned int Fb[NIN1][4];  // 8 bf16 basis per record
    __shared__ float Fsil[NIN1];                        // silu per record
    __shared__ float red[4][NHID];                      // per-seg partial sums
    __shared__ float Hf[NHID][9];                       // epilogue h-features (f32)

    const int tid  = threadIdx.x;
    const int b    = blockIdx.x;           // one batch row per block
    const int o    = tid & 127;
    const int seg  = tid >> 7;             // 0..3
    const int i0   = seg * SEGI;
    const int lane = tid & 63;

    // ---- one-time: layer-1 weights -> registers, bf16-packed, sp1 folded ----
    unsigned int cw[SEGI][4];   // coef1*sp1, 8 bf16 per i
    unsigned int swp[SEGI / 2]; // sb1 pairs
    #pragma unroll
    for (int ii = 0; ii < SEGI; ++ii) {
        const float4* cp = (const float4*)(coef1 + (size_t)((i0 + ii) * NHID + o) * 8);
        float sp = sp1[(i0 + ii) * NHID + o];
        float4 a = cp[0], c = cp[1];
        cw[ii][0] = packbf(sp * a.x, sp * a.y);
        cw[ii][1] = packbf(sp * a.z, sp * a.w);
        cw[ii][2] = packbf(sp * c.x, sp * c.y);
        cw[ii][3] = packbf(sp * c.z, sp * c.w);
    }
    #pragma unroll
    for (int p = 0; p < SEGI / 2; ++p)
        swp[p] = packbf(sb1[(i0 + 2 * p) * NHID + o], sb1[(i0 + 2 * p + 1) * NHID + o]);

    ((float*)red)[tid] = 0.f;   // h0 = 0 (red is exactly 512 floats)
    float xv = (tid < NIN) ? x[(size_t)b * SEQT * NIN + tid] : 0.f;
    __syncthreads();

    for (int t = 0; t < SEQT; ++t) {
        // ---- phase 1: features for all 160 inputs ----
        if (tid < NIN1) {
            float c;
            if (tid < NIN) c = xv;
            else {
                int hi = tid - NIN;
                c = red[0][hi] + red[1][hi] + red[2][hi] + red[3][hi];
            }
            float sil = c / (1.f + __expf(-c));
            float b4[4]; int js;
            spline_feat(c, b4, &js);
            float e[8];
            #pragma unroll
            for (int k = 0; k < 8; ++k) {
                int d = k - js;
                e[k] = (d >= 0 && d < 4) ? b4[d] : 0.f;
            }
            uint4 pk;
            pk.x = packbf(e[0], e[1]); pk.y = packbf(e[2], e[3]);
            pk.z = packbf(e[4], e[5]); pk.w = packbf(e[6], e[7]);
            *(uint4*)&Fb[tid][0] = pk;
            Fsil[tid] = sil;
        }
        if (tid < NIN) {   // prefetch next timestep's x (latency hidden over phase 2)
            int tn = (t + 1 < SEQT) ? (t + 1) : t;
            xv = x[((size_t)b * SEQT + tn) * NIN + tid];
        }
        __syncthreads();

        // ---- phase 2: register-resident weights x LDS-broadcast features ----
        float vsil = Fsil[i0 + (lane < SEGI ? lane : 0)];  // lane-parallel silu preload
        float ac0 = 0.f, ac1 = 0.f, ac2 = 0.f, ac3 = 0.f;
        #pragma unroll
        for (int p = 0; p < SEGI / 2; ++p) {
            unsigned int sbp = swp[p];
            float sb_lo = __uint_as_float(sbp << 16);
            float sb_hi = __uint_as_float(sbp & 0xffff0000u);
            {
                const int ii = 2 * p;
                float sl = __int_as_float(__builtin_amdgcn_readlane(__float_as_int(vsil), ii));
                uint4 bb = *(const uint4*)&Fb[i0 + ii][0];   // wave-uniform broadcast
                ac0 = __builtin_fmaf(sl, sb_lo, ac0);
                ac0 = dot2w(bb.x, cw[ii][0], ac0);
                ac1 = dot2w(bb.y, cw[ii][1], ac1);
                ac2 = dot2w(bb.z, cw[ii][2], ac2);
                ac3 = dot2w(bb.w, cw[ii][3], ac3);
            }
            {
                const int ii = 2 * p + 1;
                float sl = __int_as_float(__builtin_amdgcn_readlane(__float_as_int(vsil), ii));
                uint4 bb = *(const uint4*)&Fb[i0 + ii][0];
                ac1 = __builtin_fmaf(sl, sb_hi, ac1);
                ac0 = dot2w(bb.x, cw[ii][0], ac0);
                ac1 = dot2w(bb.y, cw[ii][1], ac1);
                ac2 = dot2w(bb.z, cw[ii][2], ac2);
                ac3 = dot2w(bb.w, cw[ii][3], ac3);
            }
        }
        red[seg][o] = (ac0 + ac1) + (ac2 + ac3);
        __syncthreads();
    }

    // ---- layer 2 on final h only (fp32, matches round-3-verified math) ----
    if (tid < NHID) {
        float c = red[0][tid] + red[1][tid] + red[2][tid] + red[3][tid];
        float sil = c / (1.f + __expf(-c));
        float b4[4]; int js;
        spline_feat(c, b4, &js);
        #pragma unroll
        for (int k = 0; k < 8; ++k) {
            int d = k - js;
            Hf[tid][k] = (d >= 0 && d < 4) ? b4[d] : 0.f;
        }
        Hf[tid][8] = sil;
    }
    __syncthreads();
    if (tid < 128) {
        int o2 = tid & 15, isg = tid >> 4;     // 8 i-groups of 16
        float acc = 0.f;
        for (int q = 0; q < 16; ++q) {
            int i = isg * 16 + q;
            const float* c2 = coef2 + (size_t)(i * NOUT + o2) * 8;
            float s = 0.f;
            #pragma unroll
            for (int k = 0; k < 8; ++k) s += Hf[i][k] * c2[k];
            acc += Hf[i][8] * sb2[i * NOUT + o2] + sp2[i * NOUT + o2] * s;
        }
        ((float*)red)[isg * 16 + o2] = acc;
    }
    __syncthreads();
    if (tid < NOUT) {
        float a = 0.f;
        #pragma unroll
        for (int g = 0; g < 8; ++g) a += ((float*)red)[g * 16 + tid];
        out[(size_t)b * NOUT + tid] = a;
    }
}

extern "C" void kernel_launch(void* const* d_in, const int* in_sizes, int n_in,
                              void* d_out, int out_size, void* d_ws, size_t ws_size,
                              hipStream_t stream) {
    kan_seq<<<NB, 512, 0, stream>>>(
        (const float*)d_in[0], (const float*)d_in[1], (const float*)d_in[2],
        (const float*)d_in[3], (const float*)d_in[4], (const float*)d_in[5],
        (const float*)d_in[6], (float*)d_out);
}

// Round 5
// 1063.037 us; speedup vs baseline: 14.6513x; 1.0197x over previous
//
#include <hip/hip_runtime.h>
#include <hip/hip_bf16.h>

#define NIN 32
#define NHID 128
#define NOUT 16
#define NIN1 160   // NIN+NHID
#define SEQT 512
#define NB 256
#define SEGI 40    // i's per segment (4 segments x 128 o = 512 threads)

#if defined(__has_builtin)
#if __has_builtin(__builtin_amdgcn_fdot2_f32_bf16)
#define HAVE_DOT2BF 1
#endif
#endif
#ifndef HAVE_DOT2BF
#define HAVE_DOT2BF 0
#endif

// manual RNE f32->bf16 (inputs are finite/sane here)
__device__ __forceinline__ unsigned int f2bfbits(float f) {
    unsigned int u = __float_as_uint(f);
    return (u + 0x7fffu + ((u >> 16) & 1u)) >> 16;
}
__device__ __forceinline__ unsigned int packbf(float lo, float hi) {
    return f2bfbits(lo) | (f2bfbits(hi) << 16);
}

#if HAVE_DOT2BF
typedef __bf16 bf16x2 __attribute__((ext_vector_type(2)));
__device__ __forceinline__ float dot2w(unsigned int a, unsigned int b, float c) {
    return __builtin_amdgcn_fdot2_f32_bf16(__builtin_bit_cast(bf16x2, a),
                                           __builtin_bit_cast(bf16x2, b), c, false);
}
#else
__device__ __forceinline__ float dot2w(unsigned int a, unsigned int b, float c) {
    float alo = __uint_as_float(a << 16), ahi = __uint_as_float(a & 0xffff0000u);
    float blo = __uint_as_float(b << 16), bhi = __uint_as_float(b & 0xffff0000u);
    return __builtin_fmaf(ahi, bhi, __builtin_fmaf(alo, blo, c));
}
#endif

// Knots: t_m = -8.8 + 1.6*m (G=5, K=3, range [-4,4]); verified in round-3/4 PASS.
__device__ __forceinline__ void spline_feat(float c, float* out4, int* jst) {
    const float t0 = -8.8f, hh = 1.6f;
    int m0 = (int)floorf((c - t0) / hh);
    bool valid = (m0 >= 0) && (m0 <= 10);
    float v0 = 1.f, v1 = 0.f, v2 = 0.f, v3 = 0.f;
    #pragma unroll
    for (int d = 1; d <= 3; ++d) {
        float inv = 1.f / (d * hh);
        float nv[4];
        float pv[4] = {v0, v1, v2, v3};
        #pragma unroll
        for (int r = 3; r >= 0; --r) {
            if (r > d) { nv[r] = 0.f; continue; }
            int m = m0 - d + r;
            float tm = t0 + hh * (float)m;
            float left  = (r >= 1) ? pv[r-1] : 0.f;
            float right = (r <= d-1) ? pv[r] : 0.f;
            nv[r] = ((c - tm) * left + (tm + hh * (float)(d+1) - c) * right) * inv;
        }
        v0 = nv[0]; v1 = nv[1]; v2 = nv[2]; v3 = nv[3];
    }
    float v[4] = {v0, v1, v2, v3};
    int jb = m0 - 3;
    int js = jb < 0 ? 0 : (jb > 4 ? 4 : jb);
    int sh = js - jb;
    #pragma unroll
    for (int r = 0; r < 4; ++r) {
        int rs = r + sh;
        out4[r] = (valid && rs >= 0 && rs <= 3) ? v[rs] : 0.f;
    }
    *jst = js;
}

// fast silu: 1-ulp rcp is fine (features are bf16-rounded anyway; epilogue err ~1e-7)
__device__ __forceinline__ float fsilu(float c) {
    return c * __builtin_amdgcn_rcpf(1.f + __expf(-c));
}

// X-macro: 20 weight pairs per thread (covers 40 i's), ALL named scalars -> no alloca,
// nothing the compiler can demote to scratch.
#define R20(X) X(0) X(1) X(2) X(3) X(4) X(5) X(6) X(7) X(8) X(9) \
               X(10) X(11) X(12) X(13) X(14) X(15) X(16) X(17) X(18) X(19)

__attribute__((amdgpu_waves_per_eu(2, 2)))   // pin EXACTLY 2 waves/EU -> 256-VGPR budget
__global__ void __launch_bounds__(512)
kan_seq(const float* __restrict__ x,
        const float* __restrict__ coef1,
        const float* __restrict__ sb1,
        const float* __restrict__ sp1,
        const float* __restrict__ coef2,
        const float* __restrict__ sb2,
        const float* __restrict__ sp2,
        float* __restrict__ out)
{
    __shared__ __align__(16) unsigned int Fb[NIN1][4];  // 8 bf16 basis per record
    __shared__ float Fsil[NIN1];                        // silu per record
    __shared__ float red[4][NHID];                      // per-seg partial sums
    __shared__ float Hf[NHID][9];                       // epilogue h-features (f32)

    const int tid  = threadIdx.x;
    const int b    = blockIdx.x;           // one batch row per block
    const int o    = tid & 127;
    const int seg  = tid >> 7;             // 0..3
    const int i0   = seg * SEGI;
    const int lane = tid & 63;

    // ---- one-time: layer-1 weights -> NAMED registers, bf16-packed, sp1 folded ----
#define DECLP(p) uint4 wA##p, wB##p; unsigned int sbp##p;
    R20(DECLP)
#undef DECLP

#define INITP(p) { \
    const int iA = i0 + 2 * (p), iB = i0 + 2 * (p) + 1; \
    const float4* ca = (const float4*)(coef1 + (size_t)(iA * NHID + o) * 8); \
    const float4* cb = (const float4*)(coef1 + (size_t)(iB * NHID + o) * 8); \
    float spA = sp1[iA * NHID + o], spB = sp1[iB * NHID + o]; \
    float4 a0 = ca[0], a1 = ca[1], b0v = cb[0], b1v = cb[1]; \
    wA##p = make_uint4(packbf(spA * a0.x, spA * a0.y), packbf(spA * a0.z, spA * a0.w), \
                       packbf(spA * a1.x, spA * a1.y), packbf(spA * a1.z, spA * a1.w)); \
    wB##p = make_uint4(packbf(spB * b0v.x, spB * b0v.y), packbf(spB * b0v.z, spB * b0v.w), \
                       packbf(spB * b1v.x, spB * b1v.y), packbf(spB * b1v.z, spB * b1v.w)); \
    sbp##p = packbf(sb1[iA * NHID + o], sb1[iB * NHID + o]); }
    R20(INITP)
#undef INITP

    ((float*)red)[tid] = 0.f;   // h0 = 0 (red is exactly 512 floats)
    float xv = (tid < NIN) ? x[(size_t)b * SEQT * NIN + tid] : 0.f;
    __syncthreads();

    for (int t = 0; t < SEQT; ++t) {
        // ---- phase 1: features (silu + sparse basis) for all 160 inputs ----
        if (tid < NIN1) {
            float c;
            if (tid < NIN) c = xv;
            else {
                int hi = tid - NIN;
                c = red[0][hi] + red[1][hi] + red[2][hi] + red[3][hi];
            }
            float sil = fsilu(c);
            float b4[4]; int js;
            spline_feat(c, b4, &js);
            float e[8];
            #pragma unroll
            for (int k = 0; k < 8; ++k) {
                int d = k - js;
                e[k] = (d >= 0 && d < 4) ? b4[d] : 0.f;
            }
            uint4 pk;
            pk.x = packbf(e[0], e[1]); pk.y = packbf(e[2], e[3]);
            pk.z = packbf(e[4], e[5]); pk.w = packbf(e[6], e[7]);
            *(uint4*)&Fb[tid][0] = pk;
            Fsil[tid] = sil;
        }
        if (tid < NIN) {   // prefetch next timestep's x
            int tn = (t + 1 < SEQT) ? (t + 1) : t;
            xv = x[((size_t)b * SEQT + tn) * NIN + tid];
        }
        __syncthreads();

        // ---- phase 2: named-register weights x LDS-broadcast features ----
        float vsil = Fsil[i0 + (lane < SEGI ? lane : 0)];  // lane-parallel silu preload
        float ac0 = 0.f, ac1 = 0.f, ac2 = 0.f, ac3 = 0.f;
#define DOTP(p) { \
        float sb_lo = __uint_as_float(sbp##p << 16); \
        float sb_hi = __uint_as_float(sbp##p & 0xffff0000u); \
        float slA = __int_as_float(__builtin_amdgcn_readlane(__float_as_int(vsil), 2 * (p))); \
        float slB = __int_as_float(__builtin_amdgcn_readlane(__float_as_int(vsil), 2 * (p) + 1)); \
        uint4 bA = *(const uint4*)&Fb[i0 + 2 * (p)][0]; \
        uint4 bB = *(const uint4*)&Fb[i0 + 2 * (p) + 1][0]; \
        ac0 = __builtin_fmaf(slA, sb_lo, ac0); \
        ac0 = dot2w(bA.x, wA##p.x, ac0); ac1 = dot2w(bA.y, wA##p.y, ac1); \
        ac2 = dot2w(bA.z, wA##p.z, ac2); ac3 = dot2w(bA.w, wA##p.w, ac3); \
        ac1 = __builtin_fmaf(slB, sb_hi, ac1); \
        ac0 = dot2w(bB.x, wB##p.x, ac0); ac1 = dot2w(bB.y, wB##p.y, ac1); \
        ac2 = dot2w(bB.z, wB##p.z, ac2); ac3 = dot2w(bB.w, wB##p.w, ac3); }
        R20(DOTP)
#undef DOTP
        red[seg][o] = (ac0 + ac1) + (ac2 + ac3);
        __syncthreads();
    }

    // ---- layer 2 on final h only (fp32; verified in rounds 3-4) ----
    if (tid < NHID) {
        float c = red[0][tid] + red[1][tid] + red[2][tid] + red[3][tid];
        float sil = fsilu(c);
        float b4[4]; int js;
        spline_feat(c, b4, &js);
        #pragma unroll
        for (int k = 0; k < 8; ++k) {
            int d = k - js;
            Hf[tid][k] = (d >= 0 && d < 4) ? b4[d] : 0.f;
        }
        Hf[tid][8] = sil;
    }
    __syncthreads();
    if (tid < 128) {
        int o2 = tid & 15, isg = tid >> 4;     // 8 i-groups of 16
        float acc = 0.f;
        for (int q = 0; q < 16; ++q) {
            int i = isg * 16 + q;
            const float* c2 = coef2 + (size_t)(i * NOUT + o2) * 8;
            float s = 0.f;
            #pragma unroll
            for (int k = 0; k < 8; ++k) s += Hf[i][k] * c2[k];
            acc += Hf[i][8] * sb2[i * NOUT + o2] + sp2[i * NOUT + o2] * s;
        }
        ((float*)red)[isg * 16 + o2] = acc;
    }
    __syncthreads();
    if (tid < NOUT) {
        float a = 0.f;
        #pragma unroll
        for (int g = 0; g < 8; ++g) a += ((float*)red)[g * 16 + tid];
        out[(size_t)b * NOUT + tid] = a;
    }
}

extern "C" void kernel_launch(void* const* d_in, const int* in_sizes, int n_in,
                              void* d_out, int out_size, void* d_ws, size_t ws_size,
                              hipStream_t stream) {
    kan_seq<<<NB, 512, 0, stream>>>(
        (const float*)d_in[0], (const float*)d_in[1], (const float*)d_in[2],
        (const float*)d_in[3], (const float*)d_in[4], (const float*)d_in[5],
        (const float*)d_in[6], (float*)d_out);
}